// Round 12
// baseline (929.432 us; speedup 1.0000x reference)
//
#include <hip/hip_runtime.h>
#include <hip/hip_cooperative_groups.h>
#include <hip/hip_fp16.h>
#include <math.h>

namespace cg = cooperative_groups;

// GAT 2-layer, N=50000, E=800000 (+N self loops), IN=128, HID=32, HEADS=4, OUT=32
#define NN   50000
#define EE   800000
#define ETOT 850000          // EE + NN
#define NEG  0.2f
#define L1_NB 782            // ceil(NN/64) node-blocks per head
#define L1_TASKS (L1_NB * 4) // 3128 lin1 wave-tasks
#define W_TASKS (L1_TASKS * 5) // 15640: groups of 5 = 1 lin1 + 4 fill

// -------- workspace layout (element offsets, 4B units; ints/halfs alias floats) --------
#define O_DEG    0           //    50,000  in-degree (int, excl self-loop; zeroed in-kernel)
#define O_EAPART 50000       //     2,048  per-block edge-attr partials (float)
#define O_BLKSUM 52048       //     2,048  scan block totals (int)
#define O_BLKOFF 54096       //     2,048  scan block offsets (int)
#define O_COEF   56144       //         8  coef1[4], coef2 at [4], eamean at [5]
#define O_ROWPTR 56152       //    50,004  CSR row pointers (int)
#define O_RANK   106156      //   800,000  rank of edge within its dst row (int)
#define O_CSRSRC 906156      //   850,000  src node per CSR slot (int)
#define O_EASLOT 1756156     //   850,000  edge attr in CSR slot order (float)
#define O_ASRC1  2606156     //   200,000  per-node src logits layer1 [N][4]
#define O_ADST1  2806156     //   200,000  per-node dst logits layer1 [N][4]
#define O_XLH    3006156     // 3,200,000  layer-1 features fp16 [N][128]
#define O_OUT1   6206156     // 6,400,000  layer-1 agg output fp32 [N][128]
#define O_HLH    12606156    //   800,000  layer-2 features fp16 [N][32]
#define O_ASRC2  13406156    //    50,000  per-node src logits layer2
#define O_ADST2  13456156    //    50,000  per-node dst logits layer2
#define WS_ELEMS 13506156    // ~54 MB

struct MegaParams {
  const float* x; const int* ei; const float* eattr;
  const float* W1; const float* a1s; const float* a1d;
  const float* lew1; const float* ae1; const float* bias1;
  const float* W2; const float* a2s; const float* a2d;
  const float* lew2; const float* ae2; const float* bias2;
  float* out;
  int* deg; float* eapart; int* blksum; int* blkoff; float* coef;
  int* rowptr; int* rank; int* csr_src; float* ea_slot;
  float* asrc1; float* adst1; __half* xlh; float* out1;
  __half* hlh; float* asrc2; float* adst2;
};

__device__ __forceinline__ int wave_incl_scan(int v, int lane) {
  #pragma unroll
  for (int o = 1; o < 64; o <<= 1) {
    int u = __shfl_up(v, o, 64);
    if (lane >= o) v += u;
  }
  return v;
}

// 32 FMAs against one uniform W row of 32 floats
#define GEMM_STEP(WB, K, XS) {                                              \
    const float4* Wr = (const float4*)((WB) + (size_t)(K));                 \
    _Pragma("unroll")                                                       \
    for (int j4 = 0; j4 < 8; ++j4) {                                        \
      float4 wv2 = Wr[j4];                                                  \
      acc[j4 * 4 + 0] += (XS) * wv2.x;                                      \
      acc[j4 * 4 + 1] += (XS) * wv2.y;                                      \
      acc[j4 * 4 + 2] += (XS) * wv2.z;                                      \
      acc[j4 * 4 + 3] += (XS) * wv2.w;                                      \
    } }

// ============================ THE MEGA-KERNEL =============================
// One cooperative launch; grid.sync() replaces ~9 dispatch gaps (~11 us each).
__global__ __launch_bounds__(256, 4) void k_mega(MegaParams p) {
  cg::grid_group gg = cg::this_grid();
  __shared__ int   wsum[4];
  __shared__ float fred[4];
  const int t = threadIdx.x;
  const int bid = blockIdx.x;
  const int nblk = (int)gridDim.x;
  const int gsz = nblk * 256;
  const int gid = bid * 256 + t;
  const int lane = t & 63, wv = t >> 6;

  // ---- P0: zero deg (replaces hipMemsetAsync dispatch) ----
  for (int i = gid; i < NN; i += gsz) p.deg[i] = 0;
  gg.sync();

  // ---- P1: degree count + rank (atomic return = rank) + per-block ea partial ----
  {
    float s = 0.f;
    for (int e = gid; e < EE; e += gsz) {
      s += p.eattr[e];
      p.rank[e] = atomicAdd(p.deg + p.ei[EE + e], 1);
    }
    #pragma unroll
    for (int o = 32; o > 0; o >>= 1) s += __shfl_down(s, o, 64);
    if (lane == 0) fred[wv] = s;
    __syncthreads();
    if (t == 0) p.eapart[bid] = fred[0] + fred[1] + fred[2] + fred[3];
  }
  gg.sync();

  // ---- P2 (block 0): reduce eapart -> eamean (coef[5]); coef[0..4] ----
  if (bid == 0) {
    float fs = 0.f;
    for (int i = t; i < nblk; i += 256) fs += p.eapart[i];
    #pragma unroll
    for (int o = 32; o > 0; o >>= 1) fs += __shfl_down(fs, o, 64);
    __syncthreads();               // fred free from P1
    if (lane == 0) fred[wv] = fs;
    __syncthreads();
    if (t == 0) p.coef[5] = (fred[0] + fred[1] + fred[2] + fred[3]) * (1.f / EE);
    if (t < 128) {
      float pp = p.lew1[t] * p.ae1[t];
      #pragma unroll
      for (int o = 16; o > 0; o >>= 1) pp += __shfl_down(pp, o, 32);
      if ((t & 31) == 0) p.coef[t >> 5] = pp;
      if (t < 32) {
        float q = p.lew2[t] * p.ae2[t];
        #pragma unroll
        for (int o = 16; o > 0; o >>= 1) q += __shfl_down(q, o, 32);
        if (t == 0) p.coef[4] = q;
      }
    }
  }
  gg.sync();

  // ---- P3: per-block scan of (deg+1) -> local exclusive in rowptr; totals -> blksum ----
  {
    int i = gid;
    int v = (i < NN) ? p.deg[i] + 1 : 0;       // +1 = self-loop
    int incl = wave_incl_scan(v, lane);
    if (lane == 63) wsum[wv] = incl;
    __syncthreads();
    int off = 0;
    #pragma unroll
    for (int k = 0; k < 4; ++k) if (k < wv) off += wsum[k];
    incl += off;
    if (i < NN) p.rowptr[i] = incl - v;
    if (t == 255) p.blksum[bid] = incl;
  }
  gg.sync();

  // ---- P4 (block 0): exclusive scan of blksum -> blkoff ----
  if (bid == 0) {
    int carry = 0;
    for (int c0 = 0; c0 < nblk; c0 += 256) {
      __syncthreads();             // wsum reuse guard
      int i = c0 + t;
      int v = (i < nblk) ? p.blksum[i] : 0;
      int incl = wave_incl_scan(v, lane);
      if (lane == 63) wsum[wv] = incl;
      __syncthreads();
      int off = 0, tot = 0;
      #pragma unroll
      for (int k = 0; k < 4; ++k) { int w = wsum[k]; tot += w; if (k < wv) off += w; }
      if (i < nblk) p.blkoff[i] = carry + incl + off - v;
      carry += tot;
    }
  }
  gg.sync();

  // ---- P5: finalize rowptr; write deterministic self-loop at last slot of each row ----
  {
    int i = gid;
    if (i < NN) {
      int r = p.rowptr[i] + p.blkoff[bid];
      p.rowptr[i] = r;
      int slot = r + p.deg[i];
      p.csr_src[slot] = i;
      p.ea_slot[slot] = p.coef[5];             // eamean
    }
    if (gid == 0) p.rowptr[NN] = ETOT;
  }
  gg.sync();

  // ---- P6: layer-1 GEMM interleaved 1:4 with atomic-free CSR fill (wave-tasks) ----
  for (int wt = bid * 4 + wv; wt < W_TASKS; wt += nblk * 4) {
    int g5 = wt / 5, r5 = wt % 5;
    if (r5 != 0) {                             // fill task (no atomics)
      int e = (g5 * 4 + r5 - 1) * 64 + lane;
      if (e < EE) {
        int s = p.ei[e];
        int d = p.ei[EE + e];
        float ea = p.eattr[e];
        int slot = p.rowptr[d] + p.rank[e];
        p.csr_src[slot] = s;
        p.ea_slot[slot] = ea;
      }
    } else {                                   // lin1 task
      int h = g5 / L1_NB;
      int n = (g5 % L1_NB) * 64 + lane;
      int nc = n < NN ? n : NN - 1;
      const float4* xr = (const float4*)(p.x + (size_t)nc * 128);
      const float* Wh = p.W1 + h * 32;         // wave-uniform
      float acc[32];
      #pragma unroll
      for (int j = 0; j < 32; ++j) acc[j] = 0.f;
      float4 xv = xr[0];
      for (int kt = 0; kt < 32; ++kt) {
        float4 cur = xv;
        if (kt < 31) xv = xr[kt + 1];
        GEMM_STEP(Wh, (kt * 4 + 0) * 128, cur.x);
        GEMM_STEP(Wh, (kt * 4 + 1) * 128, cur.y);
        GEMM_STEP(Wh, (kt * 4 + 2) * 128, cur.z);
        GEMM_STEP(Wh, (kt * 4 + 3) * 128, cur.w);
      }
      if (n < NN) {
        __align__(16) __half hbuf[32];
        #pragma unroll
        for (int j = 0; j < 32; ++j) hbuf[j] = __float2half_rn(acc[j]);
        float4* dst = (float4*)(p.xlh + (size_t)n * 128 + h * 32);
        #pragma unroll
        for (int i4 = 0; i4 < 4; ++i4) dst[i4] = ((const float4*)hbuf)[i4];
        float ss = 0.f, sd = 0.f;
        #pragma unroll
        for (int j = 0; j < 32; ++j) {
          ss += acc[j] * p.a1s[h * 32 + j];
          sd += acc[j] * p.a1d[h * 32 + j];
        }
        p.asrc1[n * 4 + h] = ss;
        p.adst1[n * 4 + h] = sd;
      }
    }
  }
  gg.sync();

  // ---- P7: layer-1 aggregation (fused softmax), batch-4 pipelined ----
  for (int nb2 = bid; nb2 < NN / 8; nb2 += nblk) {
    int n = nb2 * 8 + (t >> 5);                // 6250*8 == NN exactly
    int l = t & 31;
    int c4 = l << 2;
    int h = l >> 3;
    float cf = p.coef[h];
    float ad = p.adst1[(size_t)n * 4 + h];
    int r0 = p.rowptr[n], r1 = p.rowptr[n + 1];
    float a0 = 0.f, a1 = 0.f, a2 = 0.f, a3 = 0.f, den = 0.f;
    for (int j = r0; j < r1; j += 4) {
      int sv[4]; float eav[4], asv[4]; uint2 raw[4];
      #pragma unroll
      for (int k = 0; k < 4; ++k) {
        int jj = (j + k < r1) ? (j + k) : (r1 - 1);
        sv[k] = p.csr_src[jj];
        eav[k] = p.ea_slot[jj];
      }
      #pragma unroll
      for (int k = 0; k < 4; ++k) {
        asv[k] = p.asrc1[(size_t)sv[k] * 4 + h];
        raw[k] = *(const uint2*)(p.xlh + (size_t)sv[k] * 128 + c4);
      }
      #pragma unroll
      for (int k = 0; k < 4; ++k) {
        float alpha = asv[k] + ad + eav[k] * cf;
        alpha = alpha > 0.f ? alpha : NEG * alpha;
        float ex = (j + k < r1) ? __expf(alpha) : 0.f;
        __half2 p0, p1;
        *(unsigned int*)&p0 = raw[k].x;
        *(unsigned int*)&p1 = raw[k].y;
        float2 f0 = __half22float2(p0), f1 = __half22float2(p1);
        a0 += ex * f0.x;
        a1 += ex * f0.y;
        a2 += ex * f1.x;
        a3 += ex * f1.y;
        den += ex;
      }
    }
    float inv = 1.f / den;
    *(float4*)(p.out1 + (size_t)n * 128 + c4) =
        make_float4(a0 * inv, a1 * inv, a2 * inv, a3 * inv);
  }
  gg.sync();

  // ---- P8: layer-2 GEMM (lane = node), single pass ----
  {
    int n = gid;
    int nc = n < NN ? n : NN - 1;
    if (gid < ((NN + 63) / 64) * 64) {         // skip idle far blocks cheaply
      const float4* xr = (const float4*)(p.out1 + (size_t)nc * 128);
      const float4* br = (const float4*)p.bias1;
      float acc[32];
      #pragma unroll
      for (int j = 0; j < 32; ++j) acc[j] = 0.f;
      float4 xv = xr[0];
      for (int kt = 0; kt < 32; ++kt) {
        float4 cur = xv;
        if (kt < 31) xv = xr[kt + 1];
        float4 b = br[kt];
        cur.x += b.x; cur.y += b.y; cur.z += b.z; cur.w += b.w;
        cur.x = cur.x > 0.f ? cur.x : (__expf(cur.x) - 1.f);   // ELU
        cur.y = cur.y > 0.f ? cur.y : (__expf(cur.y) - 1.f);
        cur.z = cur.z > 0.f ? cur.z : (__expf(cur.z) - 1.f);
        cur.w = cur.w > 0.f ? cur.w : (__expf(cur.w) - 1.f);
        GEMM_STEP(p.W2, (kt * 4 + 0) * 32, cur.x);
        GEMM_STEP(p.W2, (kt * 4 + 1) * 32, cur.y);
        GEMM_STEP(p.W2, (kt * 4 + 2) * 32, cur.z);
        GEMM_STEP(p.W2, (kt * 4 + 3) * 32, cur.w);
      }
      if (n < NN) {
        __align__(16) __half hbuf[32];
        #pragma unroll
        for (int j = 0; j < 32; ++j) hbuf[j] = __float2half_rn(acc[j]);
        float4* dst = (float4*)(p.hlh + (size_t)n * 32);
        #pragma unroll
        for (int i4 = 0; i4 < 4; ++i4) dst[i4] = ((const float4*)hbuf)[i4];
        float ps = 0.f, pd = 0.f;
        #pragma unroll
        for (int j = 0; j < 32; ++j) {
          ps += acc[j] * p.a2s[j];
          pd += acc[j] * p.a2d[j];
        }
        p.asrc2[n] = ps;
        p.adst2[n] = pd;
      }
    }
  }
  gg.sync();

  // ---- P9: layer-2 aggregation (fused softmax), batch-4 pipelined; fused bias2 ----
  for (int nb2 = bid; nb2 < (NN + 31) / 32; nb2 += nblk) {
    int n = nb2 * 32 + (t >> 3);
    if (n < NN) {
      int c4 = (t & 7) << 2;
      float cf = p.coef[4];
      float ad = p.adst2[n];
      int r0 = p.rowptr[n], r1 = p.rowptr[n + 1];
      float a0 = 0.f, a1 = 0.f, a2 = 0.f, a3 = 0.f, den = 0.f;
      for (int j = r0; j < r1; j += 4) {
        int sv[4]; float eav[4], asv[4]; uint2 raw[4];
        #pragma unroll
        for (int k = 0; k < 4; ++k) {
          int jj = (j + k < r1) ? (j + k) : (r1 - 1);
          sv[k] = p.csr_src[jj];
          eav[k] = p.ea_slot[jj];
        }
        #pragma unroll
        for (int k = 0; k < 4; ++k) {
          asv[k] = p.asrc2[sv[k]];
          raw[k] = *(const uint2*)(p.hlh + (size_t)sv[k] * 32 + c4);
        }
        #pragma unroll
        for (int k = 0; k < 4; ++k) {
          float alpha = asv[k] + ad + eav[k] * cf;
          alpha = alpha > 0.f ? alpha : NEG * alpha;
          float ex = (j + k < r1) ? __expf(alpha) : 0.f;
          __half2 p0, p1;
          *(unsigned int*)&p0 = raw[k].x;
          *(unsigned int*)&p1 = raw[k].y;
          float2 f0 = __half22float2(p0), f1 = __half22float2(p1);
          a0 += ex * f0.x;
          a1 += ex * f0.y;
          a2 += ex * f1.x;
          a3 += ex * f1.y;
          den += ex;
        }
      }
      float inv = 1.f / den;
      float4 b = *(const float4*)(p.bias2 + c4);
      *(float4*)(p.out + (size_t)n * 32 + c4) =
          make_float4(a0 * inv + b.x, a1 * inv + b.y, a2 * inv + b.z, a3 * inv + b.w);
    }
  }
}

extern "C" void kernel_launch(void* const* d_in, const int* in_sizes, int n_in,
                              void* d_out, int out_size, void* d_ws, size_t ws_size,
                              hipStream_t stream) {
  float* ws = (float*)d_ws;
  int*   wsi = (int*)d_ws;

  MegaParams p;
  p.x     = (const float*)d_in[0];
  p.ei    = (const int*)d_in[1];
  p.eattr = (const float*)d_in[2];
  p.W1    = (const float*)d_in[3];
  p.a1s   = (const float*)d_in[4];
  p.a1d   = (const float*)d_in[5];
  p.lew1  = (const float*)d_in[6];
  p.ae1   = (const float*)d_in[7];
  p.bias1 = (const float*)d_in[8];
  p.W2    = (const float*)d_in[9];
  p.a2s   = (const float*)d_in[10];
  p.a2d   = (const float*)d_in[11];
  p.lew2  = (const float*)d_in[12];
  p.ae2   = (const float*)d_in[13];
  p.bias2 = (const float*)d_in[14];
  p.out   = (float*)d_out;
  p.deg     = wsi + O_DEG;
  p.eapart  = ws + O_EAPART;
  p.blksum  = wsi + O_BLKSUM;
  p.blkoff  = wsi + O_BLKOFF;
  p.coef    = ws + O_COEF;
  p.rowptr  = wsi + O_ROWPTR;
  p.rank    = wsi + O_RANK;
  p.csr_src = wsi + O_CSRSRC;
  p.ea_slot = ws + O_EASLOT;
  p.asrc1   = ws + O_ASRC1;
  p.adst1   = ws + O_ADST1;
  p.xlh     = (__half*)(ws + O_XLH);
  p.out1    = ws + O_OUT1;
  p.hlh     = (__half*)(ws + O_HLH);
  p.asrc2   = ws + O_ASRC2;
  p.adst2   = ws + O_ADST2;

  // size grid to guaranteed co-residency (cooperative launch requirement)
  int bpc = 0;
  hipError_t err = hipOccupancyMaxActiveBlocksPerMultiprocessor(&bpc, (const void*)k_mega, 256, 0);
  if (err != hipSuccess || bpc <= 0) bpc = 2;
  if (bpc > 8) bpc = 8;                        // blksum/blkoff sized for 2048 blocks
  dim3 grid(bpc * 256);                        // 256 CUs on MI355X
  dim3 block(256);
  void* args[] = { &p };
  hipLaunchCooperativeKernel((const void*)k_mega, grid, block, args, 0, stream);
}